// Round 1
// baseline (7764.320 us; speedup 1.0000x reference)
//
#include <hip/hip_runtime.h>
#include <cstdint>

#define N_USERS 100000
#define N_ITEMS 50000
#define N_NODES (N_USERS + N_ITEMS)
#define EMB 64
#define N_EDGES 4000000
#define LN_EPS 1e-5f

// ---------------------------------------------------------------------------
// Encoder: y = LeakyReLU(LayerNorm(x @ W + b) * g + be, 0.2)
// item-per-thread: thread owns a full output row -> LN is thread-local.
// W reads are wave-uniform -> scalar loads (constant cache), no LDS needed.
// ---------------------------------------------------------------------------
template<int K>
__global__ __launch_bounds__(256) void encode_kernel(
    const float* __restrict__ X, const float* __restrict__ W,
    const float* __restrict__ b, const float* __restrict__ g,
    const float* __restrict__ be, float* __restrict__ out, int R)
{
    int item = blockIdx.x * 256 + threadIdx.x;
    if (item >= R) return;
    const float* __restrict__ xrow = X + (size_t)item * K;
    float y[EMB];
    #pragma unroll
    for (int d0 = 0; d0 < EMB; d0 += 16) {
        float acc[16];
        #pragma unroll
        for (int j = 0; j < 16; ++j) acc[j] = 0.f;
        for (int k0 = 0; k0 < K; k0 += 4) {
            float4 x4 = *reinterpret_cast<const float4*>(xrow + k0);
            float xs[4] = {x4.x, x4.y, x4.z, x4.w};
            #pragma unroll
            for (int kk = 0; kk < 4; ++kk) {
                #pragma unroll
                for (int j = 0; j < 16; ++j)
                    acc[j] = fmaf(xs[kk], W[(k0 + kk) * EMB + d0 + j], acc[j]);
            }
        }
        #pragma unroll
        for (int j = 0; j < 16; ++j) y[d0 + j] = acc[j] + b[d0 + j];
    }
    // LayerNorm (thread-local over 64 dims)
    float mu = 0.f;
    #pragma unroll
    for (int d = 0; d < EMB; ++d) mu += y[d];
    mu *= (1.f / EMB);
    float var = 0.f;
    #pragma unroll
    for (int d = 0; d < EMB; ++d) { float t = y[d] - mu; var += t * t; }
    var *= (1.f / EMB);
    float rs = rsqrtf(var + LN_EPS);
    float4* o = reinterpret_cast<float4*>(out + (size_t)item * EMB);
    #pragma unroll
    for (int q = 0; q < 16; ++q) {
        float z[4];
        #pragma unroll
        for (int u = 0; u < 4; ++u) {
            int d = q * 4 + u;
            float t = (y[d] - mu) * rs * g[d] + be[d];
            z[u] = t > 0.f ? t : 0.2f * t;
        }
        o[q] = make_float4(z[0], z[1], z[2], z[3]);
    }
}

// ---------------------------------------------------------------------------
// Column sum of an [n_rows x 64] matrix into sum[64].
// stride is a multiple of 64 -> each thread's column is fixed (tid & 63).
// ---------------------------------------------------------------------------
__global__ __launch_bounds__(256) void colsum_kernel(
    const float* __restrict__ X, int n, float* __restrict__ sum)
{
    __shared__ float s[256];
    int tid = threadIdx.x;
    float p = 0.f;
    int stride = gridDim.x * 256;
    for (int i = blockIdx.x * 256 + tid; i < n; i += stride) p += X[i];
    s[tid] = p;
    __syncthreads();
    if (tid < 64)
        unsafeAtomicAdd(&sum[tid], s[tid] + s[tid + 64] + s[tid + 128] + s[tid + 192]);
}

// ---------------------------------------------------------------------------
// hdr layout (floats): [0:64) u_sum  [64:128) um_sum  [128:192) u_mean
// [192:256) m2_vec  [256:320) pre1 = b1 + u_mean @ W1[:64]
// ---------------------------------------------------------------------------
__global__ void finalize_kernel(const float* __restrict__ aW1,
                                const float* __restrict__ ab1,
                                float* __restrict__ hdr)
{
    int d = threadIdx.x; // 64 threads
    float um = hdr[d] * (1.f / N_USERS);
    float m2 = hdr[64 + d] * (1.f / N_USERS);
    hdr[128 + d] = um;
    hdr[192 + d] = m2;
    float acc = ab1[d];
    for (int k = 0; k < EMB; ++k)
        acc = fmaf(hdr[k] * (1.f / N_USERS), aW1[k * EMB + d], acc);
    hdr[256 + d] = acc;
}

__global__ void copy_kernel(const float* __restrict__ a, float* __restrict__ o, int n4)
{
    int i = blockIdx.x * blockDim.x + threadIdx.x;
    int stride = gridDim.x * blockDim.x;
    const float4* A = reinterpret_cast<const float4*>(a);
    float4* O = reinterpret_cast<float4*>(o);
    for (; i < n4; i += stride) O[i] = A[i];
}

// ---------------------------------------------------------------------------
// Per-item: modal attention + weighted modal fusion.
// all_emb[U+i] = item_emb[i] + w0*m0[i] + w1*m1[i] + w2*m2_vec
// ---------------------------------------------------------------------------
__global__ __launch_bounds__(256) void item_fuse_kernel(
    const float* __restrict__ item_emb, const float* __restrict__ m0,
    const float* __restrict__ m1, const float* __restrict__ hdr,
    const float* __restrict__ aW1, const float* __restrict__ aW2,
    const float* __restrict__ ab2, float* __restrict__ e0)
{
    int i = blockIdx.x * 256 + threadIdx.x;
    if (i >= N_ITEMS) return;
    float ie[EMB];
    const float4* ir = reinterpret_cast<const float4*>(item_emb + (size_t)i * EMB);
    #pragma unroll
    for (int q = 0; q < 16; ++q) {
        float4 v = ir[q];
        ie[q*4+0] = v.x; ie[q*4+1] = v.y; ie[q*4+2] = v.z; ie[q*4+3] = v.w;
    }
    float s0 = ab2[0], s1 = ab2[1], s2 = ab2[2];
    #pragma unroll
    for (int d0 = 0; d0 < EMB; d0 += 16) {
        float acc[16];
        #pragma unroll
        for (int j = 0; j < 16; ++j) acc[j] = hdr[256 + d0 + j];  // pre1 (incl. b1 + u_mean part)
        #pragma unroll
        for (int k = 0; k < EMB; ++k) {
            #pragma unroll
            for (int j = 0; j < 16; ++j)
                acc[j] = fmaf(ie[k], aW1[(64 + k) * EMB + d0 + j], acc[j]);
        }
        #pragma unroll
        for (int j = 0; j < 16; ++j) {
            float t = tanhf(acc[j]);
            int d = d0 + j;
            s0 = fmaf(t, aW2[d * 3 + 0], s0);
            s1 = fmaf(t, aW2[d * 3 + 1], s1);
            s2 = fmaf(t, aW2[d * 3 + 2], s2);
        }
    }
    float mx = fmaxf(s0, fmaxf(s1, s2));
    float ew0 = expf(s0 - mx), ew1 = expf(s1 - mx), ew2 = expf(s2 - mx);
    float inv = 1.f / (ew0 + ew1 + ew2);
    float w0 = ew0 * inv, w1 = ew1 * inv, w2 = ew2 * inv;

    const float4* r0 = reinterpret_cast<const float4*>(m0 + (size_t)i * EMB);
    const float4* r1 = reinterpret_cast<const float4*>(m1 + (size_t)i * EMB);
    float4* orow = reinterpret_cast<float4*>(e0 + (size_t)(N_USERS + i) * EMB);
    #pragma unroll
    for (int q = 0; q < 16; ++q) {
        float4 a = r0[q], bq = r1[q];
        float4 res;
        res.x = ie[q*4+0] + w0*a.x + w1*bq.x + w2*hdr[192 + q*4+0];
        res.y = ie[q*4+1] + w0*a.y + w1*bq.y + w2*hdr[192 + q*4+1];
        res.z = ie[q*4+2] + w0*a.z + w1*bq.z + w2*hdr[192 + q*4+2];
        res.w = ie[q*4+3] + w0*a.w + w1*bq.w + w2*hdr[192 + q*4+3];
        orow[q] = res;
    }
}

// ---------------------------------------------------------------------------
// COO SpMM: dst[row] += val * src[col]; 16 lanes per edge, float4 gather,
// 4 hardware-fadd atomics per lane. SCALE_DIV3 folds the final /3.
// ---------------------------------------------------------------------------
template<int SCALE_DIV3>
__global__ __launch_bounds__(256) void spmm_kernel(
    const float* __restrict__ vals, const int* __restrict__ rows,
    const int* __restrict__ cols, const float* __restrict__ src,
    float* __restrict__ dst)
{
    unsigned int gt = blockIdx.x * 256u + threadIdx.x;
    unsigned int e = gt >> 4;
    if (e >= N_EDGES) return;
    int part = (gt & 15u) << 2;
    float v = vals[e];
    if (SCALE_DIV3) v *= (1.f / 3.f);
    int c = cols[e], r = rows[e];
    float4 x = *reinterpret_cast<const float4*>(src + (size_t)c * EMB + part);
    float* d = dst + (size_t)r * EMB + part;
    unsafeAtomicAdd(d + 0, v * x.x);
    unsafeAtomicAdd(d + 1, v * x.y);
    unsafeAtomicAdd(d + 2, v * x.z);
    unsafeAtomicAdd(d + 3, v * x.w);
}

__global__ void axpb3_kernel(const float* __restrict__ a, const float* __restrict__ b,
                             float* __restrict__ o, int n4)
{
    int i = blockIdx.x * blockDim.x + threadIdx.x;
    int stride = gridDim.x * blockDim.x;
    const float4* A = reinterpret_cast<const float4*>(a);
    const float4* B = reinterpret_cast<const float4*>(b);
    float4* O = reinterpret_cast<float4*>(o);
    for (; i < n4; i += stride) {
        float4 x = A[i], y = B[i];
        O[i] = make_float4((x.x + y.x) * (1.f / 3.f), (x.y + y.y) * (1.f / 3.f),
                           (x.z + y.z) * (1.f / 3.f), (x.w + y.w) * (1.f / 3.f));
    }
}

extern "C" void kernel_launch(void* const* d_in, const int* in_sizes, int n_in,
                              void* d_out, int out_size, void* d_ws, size_t ws_size,
                              hipStream_t stream)
{
    const float* user_emb = (const float*)d_in[0];
    const float* item_emb = (const float*)d_in[1];
    const float* mf0 = (const float*)d_in[2];
    const float* mf1 = (const float*)d_in[3];
    const float* mf2 = (const float*)d_in[4];
    const float* W0  = (const float*)d_in[5];
    const float* b0  = (const float*)d_in[6];
    const float* g0  = (const float*)d_in[7];
    const float* be0 = (const float*)d_in[8];
    const float* W1  = (const float*)d_in[9];
    const float* b1  = (const float*)d_in[10];
    const float* g1  = (const float*)d_in[11];
    const float* be1 = (const float*)d_in[12];
    const float* W2  = (const float*)d_in[13];
    const float* b2  = (const float*)d_in[14];
    const float* g2  = (const float*)d_in[15];
    const float* be2 = (const float*)d_in[16];
    const float* aW1 = (const float*)d_in[17];
    const float* ab1 = (const float*)d_in[18];
    const float* aW2 = (const float*)d_in[19];
    const float* ab2 = (const float*)d_in[20];
    const float* avals = (const float*)d_in[21];
    const int* arows = (const int*)d_in[22];
    const int* acols = (const int*)d_in[23];
    float* out = (float*)d_out;

    float* ws  = (float*)d_ws;
    float* hdr = ws;                                   // 512 floats
    float* m0b = ws + 512;                             // 50000*64
    float* m1b = m0b + (size_t)N_ITEMS * EMB;          // 50000*64
    float* e0  = m1b + (size_t)N_ITEMS * EMB;          // 150000*64
    float* e1  = e0 + (size_t)N_NODES * EMB;           // 150000*64
    float* umb = e1;  // um (100000*64) aliases e1; consumed before e1 is zeroed

    hipMemsetAsync(hdr, 0, 128 * sizeof(float), stream);
    colsum_kernel<<<256, 256, 0, stream>>>(user_emb, N_USERS * EMB, hdr);         // u_sum
    encode_kernel<128><<<(N_USERS + 255) / 256, 256, 0, stream>>>(mf2, W2, b2, g2, be2, umb, N_USERS);
    colsum_kernel<<<256, 256, 0, stream>>>(umb, N_USERS * EMB, hdr + 64);         // um_sum
    finalize_kernel<<<1, 64, 0, stream>>>(aW1, ab1, hdr);
    encode_kernel<768><<<(N_ITEMS + 255) / 256, 256, 0, stream>>>(mf0, W0, b0, g0, be0, m0b, N_ITEMS);
    encode_kernel<384><<<(N_ITEMS + 255) / 256, 256, 0, stream>>>(mf1, W1, b1, g1, be1, m1b, N_ITEMS);
    copy_kernel<<<1024, 256, 0, stream>>>(user_emb, e0, N_USERS * EMB / 4);
    item_fuse_kernel<<<(N_ITEMS + 255) / 256, 256, 0, stream>>>(item_emb, m0b, m1b, hdr, aW1, aW2, ab2, e0);
    hipMemsetAsync(e1, 0, (size_t)N_NODES * EMB * sizeof(float), stream);
    spmm_kernel<0><<<(N_EDGES * 16) / 256, 256, 0, stream>>>(avals, arows, acols, e0, e1);
    axpb3_kernel<<<2048, 256, 0, stream>>>(e0, e1, out, N_NODES * EMB / 4);
    spmm_kernel<1><<<(N_EDGES * 16) / 256, 256, 0, stream>>>(avals, arows, acols, e1, out);
}

// Round 2
// 2121.367 us; speedup vs baseline: 3.6601x; 3.6601x over previous
//
#include <hip/hip_runtime.h>
#include <cstdint>

#define N_USERS 100000
#define N_ITEMS 50000
#define N_NODES (N_USERS + N_ITEMS)
#define EMB 64
#define N_EDGES 4000000
#define LN_EPS 1e-5f

// ---------------------------------------------------------------------------
// Encoder: y = LeakyReLU(LayerNorm(x @ W + b) * g + be, 0.2)
// item-per-thread: thread owns a full output row -> LN is thread-local.
// ---------------------------------------------------------------------------
template<int K>
__global__ __launch_bounds__(256) void encode_kernel(
    const float* __restrict__ X, const float* __restrict__ W,
    const float* __restrict__ b, const float* __restrict__ g,
    const float* __restrict__ be, float* __restrict__ out, int R)
{
    int item = blockIdx.x * 256 + threadIdx.x;
    if (item >= R) return;
    const float* __restrict__ xrow = X + (size_t)item * K;
    float y[EMB];
    #pragma unroll
    for (int d0 = 0; d0 < EMB; d0 += 16) {
        float acc[16];
        #pragma unroll
        for (int j = 0; j < 16; ++j) acc[j] = 0.f;
        for (int k0 = 0; k0 < K; k0 += 4) {
            float4 x4 = *reinterpret_cast<const float4*>(xrow + k0);
            float xs[4] = {x4.x, x4.y, x4.z, x4.w};
            #pragma unroll
            for (int kk = 0; kk < 4; ++kk) {
                #pragma unroll
                for (int j = 0; j < 16; ++j)
                    acc[j] = fmaf(xs[kk], W[(k0 + kk) * EMB + d0 + j], acc[j]);
            }
        }
        #pragma unroll
        for (int j = 0; j < 16; ++j) y[d0 + j] = acc[j] + b[d0 + j];
    }
    float mu = 0.f;
    #pragma unroll
    for (int d = 0; d < EMB; ++d) mu += y[d];
    mu *= (1.f / EMB);
    float var = 0.f;
    #pragma unroll
    for (int d = 0; d < EMB; ++d) { float t = y[d] - mu; var += t * t; }
    var *= (1.f / EMB);
    float rs = rsqrtf(var + LN_EPS);
    float4* o = reinterpret_cast<float4*>(out + (size_t)item * EMB);
    #pragma unroll
    for (int q = 0; q < 16; ++q) {
        float z[4];
        #pragma unroll
        for (int u = 0; u < 4; ++u) {
            int d = q * 4 + u;
            float t = (y[d] - mu) * rs * g[d] + be[d];
            z[u] = t > 0.f ? t : 0.2f * t;
        }
        o[q] = make_float4(z[0], z[1], z[2], z[3]);
    }
}

__global__ __launch_bounds__(256) void colsum_kernel(
    const float* __restrict__ X, int n, float* __restrict__ sum)
{
    __shared__ float s[256];
    int tid = threadIdx.x;
    float p = 0.f;
    int stride = gridDim.x * 256;
    for (int i = blockIdx.x * 256 + tid; i < n; i += stride) p += X[i];
    s[tid] = p;
    __syncthreads();
    if (tid < 64)
        unsafeAtomicAdd(&sum[tid], s[tid] + s[tid + 64] + s[tid + 128] + s[tid + 192]);
}

// hdr: [0:64) u_sum [64:128) um_sum [128:192) u_mean [192:256) m2_vec [256:320) pre1
__global__ void finalize_kernel(const float* __restrict__ aW1,
                                const float* __restrict__ ab1,
                                float* __restrict__ hdr)
{
    int d = threadIdx.x; // 64 threads
    float um = hdr[d] * (1.f / N_USERS);
    float m2 = hdr[64 + d] * (1.f / N_USERS);
    hdr[128 + d] = um;
    hdr[192 + d] = m2;
    float acc = ab1[d];
    for (int k = 0; k < EMB; ++k)
        acc = fmaf(hdr[k] * (1.f / N_USERS), aW1[k * EMB + d], acc);
    hdr[256 + d] = acc;
}

__global__ void copy_kernel(const float* __restrict__ a, float* __restrict__ o, int n4)
{
    int i = blockIdx.x * blockDim.x + threadIdx.x;
    int stride = gridDim.x * blockDim.x;
    const float4* A = reinterpret_cast<const float4*>(a);
    float4* O = reinterpret_cast<float4*>(o);
    for (; i < n4; i += stride) O[i] = A[i];
}

__global__ __launch_bounds__(256) void item_fuse_kernel(
    const float* __restrict__ item_emb, const float* __restrict__ m0,
    const float* __restrict__ m1, const float* __restrict__ hdr,
    const float* __restrict__ aW1, const float* __restrict__ aW2,
    const float* __restrict__ ab2, float* __restrict__ e0)
{
    int i = blockIdx.x * 256 + threadIdx.x;
    if (i >= N_ITEMS) return;
    float ie[EMB];
    const float4* ir = reinterpret_cast<const float4*>(item_emb + (size_t)i * EMB);
    #pragma unroll
    for (int q = 0; q < 16; ++q) {
        float4 v = ir[q];
        ie[q*4+0] = v.x; ie[q*4+1] = v.y; ie[q*4+2] = v.z; ie[q*4+3] = v.w;
    }
    float s0 = ab2[0], s1 = ab2[1], s2 = ab2[2];
    #pragma unroll
    for (int d0 = 0; d0 < EMB; d0 += 16) {
        float acc[16];
        #pragma unroll
        for (int j = 0; j < 16; ++j) acc[j] = hdr[256 + d0 + j];
        #pragma unroll
        for (int k = 0; k < EMB; ++k) {
            #pragma unroll
            for (int j = 0; j < 16; ++j)
                acc[j] = fmaf(ie[k], aW1[(64 + k) * EMB + d0 + j], acc[j]);
        }
        #pragma unroll
        for (int j = 0; j < 16; ++j) {
            float t = tanhf(acc[j]);
            int d = d0 + j;
            s0 = fmaf(t, aW2[d * 3 + 0], s0);
            s1 = fmaf(t, aW2[d * 3 + 1], s1);
            s2 = fmaf(t, aW2[d * 3 + 2], s2);
        }
    }
    float mx = fmaxf(s0, fmaxf(s1, s2));
    float ew0 = expf(s0 - mx), ew1 = expf(s1 - mx), ew2 = expf(s2 - mx);
    float inv = 1.f / (ew0 + ew1 + ew2);
    float w0 = ew0 * inv, w1 = ew1 * inv, w2 = ew2 * inv;

    const float4* r0 = reinterpret_cast<const float4*>(m0 + (size_t)i * EMB);
    const float4* r1 = reinterpret_cast<const float4*>(m1 + (size_t)i * EMB);
    float4* orow = reinterpret_cast<float4*>(e0 + (size_t)(N_USERS + i) * EMB);
    #pragma unroll
    for (int q = 0; q < 16; ++q) {
        float4 a = r0[q], bq = r1[q];
        float4 res;
        res.x = ie[q*4+0] + w0*a.x + w1*bq.x + w2*hdr[192 + q*4+0];
        res.y = ie[q*4+1] + w0*a.y + w1*bq.y + w2*hdr[192 + q*4+1];
        res.z = ie[q*4+2] + w0*a.z + w1*bq.z + w2*hdr[192 + q*4+2];
        res.w = ie[q*4+3] + w0*a.w + w1*bq.w + w2*hdr[192 + q*4+3];
        orow[q] = res;
    }
}

// ---------------------------------------------------------------------------
// On-device CSR build: histogram -> single-block scan -> scatter(packed int2)
// ---------------------------------------------------------------------------
__global__ __launch_bounds__(256) void hist_kernel(const int* __restrict__ rows,
                                                   int* __restrict__ cnt)
{
    int i = blockIdx.x * 256 + threadIdx.x;
    int stride = gridDim.x * 256;
    for (; i < N_EDGES; i += stride) atomicAdd(&cnt[rows[i]], 1);
}

__global__ __launch_bounds__(1024) void scan_kernel(const int* __restrict__ cnt,
                                                    int* __restrict__ offs)
{
    __shared__ int s[1024];
    const int CH = (N_NODES + 1023) / 1024; // 147
    int t = threadIdx.x;
    int base = t * CH;
    int sum = 0;
    for (int i = 0; i < CH; ++i) {
        int idx = base + i;
        if (idx < N_NODES) sum += cnt[idx];
    }
    s[t] = sum;
    __syncthreads();
    for (int off = 1; off < 1024; off <<= 1) {
        int v = (t >= off) ? s[t - off] : 0;
        __syncthreads();
        s[t] += v;
        __syncthreads();
    }
    int run = (t == 0) ? 0 : s[t - 1]; // exclusive base for this chunk
    for (int i = 0; i < CH; ++i) {
        int idx = base + i;
        if (idx < N_NODES) { offs[idx] = run; run += cnt[idx]; }
    }
}

// scatter bumps offs[r]: afterwards offs[r] == end-of-row-r (inclusive prefix)
__global__ __launch_bounds__(256) void scatter_kernel(
    const float* __restrict__ vals, const int* __restrict__ rows,
    const int* __restrict__ cols, int* __restrict__ offs,
    int2* __restrict__ edges)
{
    int i = blockIdx.x * 256 + threadIdx.x;
    int stride = gridDim.x * 256;
    for (; i < N_EDGES; i += stride) {
        int r = rows[i];
        int pos = atomicAdd(&offs[r], 1);
        edges[pos] = make_int2(cols[i], __float_as_int(vals[i]));
    }
}

// ---------------------------------------------------------------------------
// CSR SpMM: one 64-lane wave per row, lane = dim. Coalesced 256B gathers,
// no atomics. FINAL variant fuses out = (e0 + e1 + A·e1) / 3.
// start(r) = offs[r-1] (post-scatter inclusive prefix), end(r) = offs[r].
// ---------------------------------------------------------------------------
template<int FINAL>
__global__ __launch_bounds__(256) void spmm_csr_kernel(
    const int* __restrict__ offs, const int2* __restrict__ edges,
    const float* __restrict__ src, const float* __restrict__ e0,
    const float* __restrict__ e1, float* __restrict__ dst)
{
    int r = blockIdx.x * 4 + (threadIdx.x >> 6);
    if (r >= N_NODES) return;
    int d = threadIdx.x & 63;
    int start = (r == 0) ? 0 : offs[r - 1];
    int end = offs[r];
    float acc0 = 0.f, acc1 = 0.f;
    int i = start;
    for (; i + 2 <= end; i += 2) {
        int2 p0 = edges[i], p1 = edges[i + 1];
        float v0 = __int_as_float(p0.y), v1 = __int_as_float(p1.y);
        acc0 = fmaf(v0, src[(size_t)p0.x * EMB + d], acc0);
        acc1 = fmaf(v1, src[(size_t)p1.x * EMB + d], acc1);
    }
    if (i < end) {
        int2 p = edges[i];
        acc0 = fmaf(__int_as_float(p.y), src[(size_t)p.x * EMB + d], acc0);
    }
    float s = acc0 + acc1;
    size_t idx = (size_t)r * EMB + d;
    if (FINAL)
        dst[idx] = (e0[idx] + e1[idx] + s) * (1.f / 3.f);
    else
        dst[idx] = s;
}

extern "C" void kernel_launch(void* const* d_in, const int* in_sizes, int n_in,
                              void* d_out, int out_size, void* d_ws, size_t ws_size,
                              hipStream_t stream)
{
    const float* user_emb = (const float*)d_in[0];
    const float* item_emb = (const float*)d_in[1];
    const float* mf0 = (const float*)d_in[2];
    const float* mf1 = (const float*)d_in[3];
    const float* mf2 = (const float*)d_in[4];
    const float* W0  = (const float*)d_in[5];
    const float* b0  = (const float*)d_in[6];
    const float* g0  = (const float*)d_in[7];
    const float* be0 = (const float*)d_in[8];
    const float* W1  = (const float*)d_in[9];
    const float* b1  = (const float*)d_in[10];
    const float* g1  = (const float*)d_in[11];
    const float* be1 = (const float*)d_in[12];
    const float* W2  = (const float*)d_in[13];
    const float* b2  = (const float*)d_in[14];
    const float* g2  = (const float*)d_in[15];
    const float* be2 = (const float*)d_in[16];
    const float* aW1 = (const float*)d_in[17];
    const float* ab1 = (const float*)d_in[18];
    const float* aW2 = (const float*)d_in[19];
    const float* ab2 = (const float*)d_in[20];
    const float* avals = (const float*)d_in[21];
    const int* arows = (const int*)d_in[22];
    const int* acols = (const int*)d_in[23];
    float* out = (float*)d_out;

    float* ws  = (float*)d_ws;
    float* hdr = ws;                                   // 512 floats
    float* m0b = ws + 512;                             // 50000*64
    float* m1b = m0b + (size_t)N_ITEMS * EMB;          // 50000*64
    float* e0  = m1b + (size_t)N_ITEMS * EMB;          // 150000*64
    float* e1  = e0 + (size_t)N_NODES * EMB;           // 150000*64
    int*   cnt = (int*)(e1 + (size_t)N_NODES * EMB);   // 150000 ints
    int*   offs = cnt + N_NODES;                       // 150000 ints
    int2*  edges = (int2*)(offs + N_NODES);            // 4M int2 (32 MB)
    float* umb = e1;  // um aliases e1; consumed before spmm1 writes e1

    hipMemsetAsync(hdr, 0, 128 * sizeof(float), stream);
    hipMemsetAsync(cnt, 0, N_NODES * sizeof(int), stream);

    // CSR build (independent of embedding pipeline)
    hist_kernel<<<2048, 256, 0, stream>>>(arows, cnt);
    scan_kernel<<<1, 1024, 0, stream>>>(cnt, offs);
    scatter_kernel<<<2048, 256, 0, stream>>>(avals, arows, acols, offs, edges);

    // embedding pipeline
    colsum_kernel<<<256, 256, 0, stream>>>(user_emb, N_USERS * EMB, hdr);   // u_sum
    encode_kernel<128><<<(N_USERS + 255) / 256, 256, 0, stream>>>(mf2, W2, b2, g2, be2, umb, N_USERS);
    colsum_kernel<<<256, 256, 0, stream>>>(umb, N_USERS * EMB, hdr + 64);   // um_sum
    finalize_kernel<<<1, 64, 0, stream>>>(aW1, ab1, hdr);
    encode_kernel<768><<<(N_ITEMS + 255) / 256, 256, 0, stream>>>(mf0, W0, b0, g0, be0, m0b, N_ITEMS);
    encode_kernel<384><<<(N_ITEMS + 255) / 256, 256, 0, stream>>>(mf1, W1, b1, g1, be1, m1b, N_ITEMS);
    copy_kernel<<<1024, 256, 0, stream>>>(user_emb, e0, N_USERS * EMB / 4);
    item_fuse_kernel<<<(N_ITEMS + 255) / 256, 256, 0, stream>>>(item_emb, m0b, m1b, hdr, aW1, aW2, ab2, e0);

    // two propagation layers, no atomics
    spmm_csr_kernel<0><<<(N_NODES + 3) / 4, 256, 0, stream>>>(offs, edges, e0, e0, e1, e1);
    spmm_csr_kernel<1><<<(N_NODES + 3) / 4, 256, 0, stream>>>(offs, edges, e1, e0, e1, out);
}